// Round 9
// baseline (78.795 us; speedup 1.0000x reference)
//
#include <hip/hip_runtime.h>
#include <hip/hip_cooperative_groups.h>
#include <math.h>

namespace cg = cooperative_groups;

#define DIM 4096
#define H 32
#define D 128
#define SMAX 2048
#define CHUNK 32
#define NCHUNK (SMAX / CHUNK)    // 64
#define PART_STRIDE 132          // acc[128], m, l, pad[2]
#define NBLK 1024                // 4 blocks/CU on 256 CUs — safe co-residency
#define NTHR 256

typedef float v4f __attribute__((ext_vector_type(4)));
typedef unsigned int u32;

__device__ __forceinline__ float wave_sum(float v) {
#pragma unroll
    for (int o = 32; o; o >>= 1) v += __shfl_xor(v, o);
    return v;
}

__device__ __forceinline__ void vsum1632(v4f& v) {
#pragma unroll
    for (int i = 0; i < 4; ++i) {
        float f = v[i];
        f += __shfl_xor(f, 16);
        f += __shfl_xor(f, 32);
        v[i] = f;
    }
}

// ==================== cooperative fused kernel ====================
__global__ void __launch_bounds__(NTHR, 4) fused_decode(
        const float* __restrict__ wq, const float* __restrict__ wk,
        const float* __restrict__ wv, const float* __restrict__ wo,
        const float* __restrict__ x,
        const float* __restrict__ cache_k, const float* __restrict__ cache_v,
        const int* __restrict__ pos_p,
        float* __restrict__ xq, float* __restrict__ xk, float* __restrict__ xv,
        float* __restrict__ partials, float* __restrict__ out_attn,
        float* __restrict__ y) {
    __shared__ float xs[DIM];              // 16 KB
    __shared__ float red[2][2][4];         // [parity][row01][wave]
    cg::grid_group grid = cg::this_grid();

    int t = threadIdx.x, lane = t & 63, w = t >> 6;
    int bid = blockIdx.x;
    int pos = *pos_p;

#pragma unroll
    for (int i = 0; i < 4; ++i)
        *reinterpret_cast<v4f*>(&xs[(i * 256 + t) * 4]) =
            *reinterpret_cast<const v4f*>(x + (i * 256 + t) * 4);
    __syncthreads();

    // ===== phase 1: QKV matvec + RoPE (6144 pair tasks, 6 iters/block) =====
    {
        int par = 0;
        for (int tp = bid; tp < 3 * 2048; tp += NBLK, par ^= 1) {
            int mat = tp >> 11;
            int pr  = tp & 2047;
            const float* wm = (mat == 0) ? wq : ((mat == 1) ? wk : wv);
            const float* base = wm + (size_t)pr * 2 * DIM;
            v4f wa[4], wb[4];
#pragma unroll
            for (int i = 0; i < 4; ++i) {
                wa[i] = *reinterpret_cast<const v4f*>(base + i * 1024 + t * 4);
                wb[i] = *reinterpret_cast<const v4f*>(base + DIM + i * 1024 + t * 4);
            }
            float a0 = 0.f, a1 = 0.f, a2 = 0.f, a3 = 0.f;
            float b0 = 0.f, b1 = 0.f, b2 = 0.f, b3 = 0.f;
#pragma unroll
            for (int i = 0; i < 4; ++i) {
                v4f xr = *reinterpret_cast<const v4f*>(&xs[i * 1024 + t * 4]);
                a0 = fmaf(wa[i].x, xr.x, a0);
                a1 = fmaf(wa[i].y, xr.y, a1);
                a2 = fmaf(wa[i].z, xr.z, a2);
                a3 = fmaf(wa[i].w, xr.w, a3);
                b0 = fmaf(wb[i].x, xr.x, b0);
                b1 = fmaf(wb[i].y, xr.y, b1);
                b2 = fmaf(wb[i].z, xr.z, b2);
                b3 = fmaf(wb[i].w, xr.w, b3);
            }
            float da = wave_sum((a0 + a1) + (a2 + a3));
            float db = wave_sum((b0 + b1) + (b2 + b3));
            if (lane == 0) { red[par][0][w] = da; red[par][1][w] = db; }
            __syncthreads();
            if (t == 0) {
                float d0 = red[par][0][0] + red[par][0][1] + red[par][0][2] + red[par][0][3];
                float d1 = red[par][1][0] + red[par][1][1] + red[par][1][2] + red[par][1][3];
                if (mat == 2) {
                    xv[2 * pr] = d0; xv[2 * pr + 1] = d1;
                } else {
                    int j = pr & 63;
                    float theta = powf(10000.0f, -(float)(2 * j) / (float)D);
                    float ang = (float)pos * theta;
                    float s, c;
                    sincosf(ang, &s, &c);
                    float* o = (mat == 0) ? xq : xk;
                    o[2 * pr]     = d0 * c - d1 * s;
                    o[2 * pr + 1] = d0 * s + d1 * c;
                }
            }
        }
    }
    grid.sync();

    // ===== phase 2: flash-decode partials (2048 wave tasks) =====
    {
        int gid = bid * 4 + w;
        int g = lane >> 4, gl = lane & 15;
        for (int task = gid; task < H * NCHUNK; task += NBLK * 4) {
            int h = task >> 6;
            int c = task & 63;
            int base_p = c * CHUNK;
            float* pp = partials + (size_t)task * PART_STRIDE;

            float m = -INFINITY, l = 0.f;
            v4f acc0 = {0.f, 0.f, 0.f, 0.f}, acc1 = {0.f, 0.f, 0.f, 0.f};

            if (base_p <= pos) {
                v4f q0 = *reinterpret_cast<const v4f*>(xq + h * D + gl * 8);
                v4f q1 = *reinterpret_cast<const v4f*>(xq + h * D + gl * 8 + 4);
                int p1 = min(base_p + CHUNK, pos + 1);
                for (int p = base_p + g; p < p1; p += 4) {
                    const float* kp = (p == pos) ? (xk + h * D)
                                                 : (cache_k + ((size_t)p * H + h) * D);
                    v4f k0 = *reinterpret_cast<const v4f*>(kp + gl * 8);
                    v4f k1 = *reinterpret_cast<const v4f*>(kp + gl * 8 + 4);
                    float d = q0.x * k0.x + q0.y * k0.y + q0.z * k0.z + q0.w * k0.w
                            + q1.x * k1.x + q1.y * k1.y + q1.z * k1.z + q1.w * k1.w;
                    d += __shfl_xor(d, 1);
                    d += __shfl_xor(d, 2);
                    d += __shfl_xor(d, 4);
                    d += __shfl_xor(d, 8);
                    float s = d * 0.08838834764831845f;
                    float mn = fmaxf(m, s);
                    float corr = __expf(m - mn);
                    float wgt  = __expf(s - mn);
                    const float* vp = (p == pos) ? (xv + h * D)
                                                 : (cache_v + ((size_t)p * H + h) * D);
                    v4f v0 = *reinterpret_cast<const v4f*>(vp + gl * 8);
                    v4f v1 = *reinterpret_cast<const v4f*>(vp + gl * 8 + 4);
                    l = l * corr + wgt;
                    acc0 = acc0 * corr + v0 * wgt;
                    acc1 = acc1 * corr + v1 * wgt;
                    m = mn;
                }
            }
            float mm = fmaxf(m, __shfl_xor(m, 16));
            float M  = fmaxf(mm, __shfl_xor(mm, 32));
            float wg = (m == -INFINITY) ? 0.f : __expf(m - M);
            float lw = l * wg;
            lw += __shfl_xor(lw, 16);
            lw += __shfl_xor(lw, 32);
            acc0 = acc0 * wg;
            acc1 = acc1 * wg;
            vsum1632(acc0);
            vsum1632(acc1);
            if (lane == 0) { pp[128] = M; pp[129] = lw; }
            if (lane < 16) {
                *reinterpret_cast<v4f*>(pp + gl * 8)     = acc0;
                *reinterpret_cast<v4f*>(pp + gl * 8 + 4) = acc1;
            }
        }
    }
    grid.sync();

    // ===== phase 3: combine partials per head (32 wave tasks) =====
    {
        int gid = bid * 4 + w;
        if (gid < H) {
            int h = gid;
            float m = -INFINITY;
            for (int c = 0; c < NCHUNK; ++c)
                m = fmaxf(m, partials[(size_t)(h * NCHUNK + c) * PART_STRIDE + 128]);
            float L = 0.f, a0 = 0.f, a1 = 0.f;
            for (int c = 0; c < NCHUNK; ++c) {
                const float* pp = partials + (size_t)(h * NCHUNK + c) * PART_STRIDE;
                float mw = pp[128];
                float wgt = (mw == -INFINITY) ? 0.f : __expf(mw - m);
                L += pp[129] * wgt;
                float2 a = *reinterpret_cast<const float2*>(pp + 2 * lane);
                a0 += wgt * a.x;
                a1 += wgt * a.y;
            }
            float inv = 1.f / L;
            out_attn[h * D + 2 * lane]     = a0 * inv;
            out_attn[h * D + 2 * lane + 1] = a1 * inv;
        }
    }
    grid.sync();

    // ===== phase 4: y = Wo @ out_attn (2048 pair tasks, 2 iters/block) =====
#pragma unroll
    for (int i = 0; i < 4; ++i)
        *reinterpret_cast<v4f*>(&xs[(i * 256 + t) * 4]) =
            *reinterpret_cast<const v4f*>(out_attn + (i * 256 + t) * 4);
    __syncthreads();
    {
        int par = 0;
        for (int tp = bid; tp < 2048; tp += NBLK, par ^= 1) {
            const float* base = wo + (size_t)tp * 2 * DIM;
            v4f wa[4], wb[4];
#pragma unroll
            for (int i = 0; i < 4; ++i) {
                wa[i] = *reinterpret_cast<const v4f*>(base + i * 1024 + t * 4);
                wb[i] = *reinterpret_cast<const v4f*>(base + DIM + i * 1024 + t * 4);
            }
            float a0 = 0.f, a1 = 0.f, a2 = 0.f, a3 = 0.f;
            float b0 = 0.f, b1 = 0.f, b2 = 0.f, b3 = 0.f;
#pragma unroll
            for (int i = 0; i < 4; ++i) {
                v4f xr = *reinterpret_cast<const v4f*>(&xs[i * 1024 + t * 4]);
                a0 = fmaf(wa[i].x, xr.x, a0);
                a1 = fmaf(wa[i].y, xr.y, a1);
                a2 = fmaf(wa[i].z, xr.z, a2);
                a3 = fmaf(wa[i].w, xr.w, a3);
                b0 = fmaf(wb[i].x, xr.x, b0);
                b1 = fmaf(wb[i].y, xr.y, b1);
                b2 = fmaf(wb[i].z, xr.z, b2);
                b3 = fmaf(wb[i].w, xr.w, b3);
            }
            float da = wave_sum((a0 + a1) + (a2 + a3));
            float db = wave_sum((b0 + b1) + (b2 + b3));
            if (lane == 0) { red[par][0][w] = da; red[par][1][w] = db; }
            __syncthreads();
            if (t == 0) {
                float d0 = red[par][0][0] + red[par][0][1] + red[par][0][2] + red[par][0][3];
                float d1 = red[par][1][0] + red[par][1][1] + red[par][1][2] + red[par][1][3];
                y[2 * tp]     = d0;
                y[2 * tp + 1] = d1;
            }
        }
    }
}

// ==================== fallback pipeline (R7, proven) ====================
__device__ __forceinline__ void gload_lds16(const float* g, float* l) {
    __builtin_amdgcn_global_load_lds(
        (const __attribute__((address_space(1))) u32*)g,
        (__attribute__((address_space(3))) u32*)l, 16, 0, 0);
}

__global__ void __launch_bounds__(256) qk_rope(
        const float* __restrict__ wq, const float* __restrict__ wk,
        const float* __restrict__ x, const int* __restrict__ pos_p,
        float* __restrict__ xq, float* __restrict__ xk) {
    __shared__ float buf[2 * DIM];
    __shared__ float red[2][4];
    int t = threadIdx.x, lane = t & 63, w = t >> 6;
    int bid = blockIdx.x;
    bool isq = bid < 2048;
    int pr = bid & 2047;
    const float* base = (isq ? wq : wk) + (size_t)pr * 2 * DIM;

    v4f xr[4];
#pragma unroll
    for (int i = 0; i < 4; ++i)
        xr[i] = *reinterpret_cast<const v4f*>(x + i * 1024 + t * 4);

#pragma unroll
    for (int i = 0; i < 8; ++i)
        gload_lds16(base + i * 1024 + t * 4, &buf[i * 1024 + t * 4]);

    __syncthreads();

    float a0 = 0.f, a1 = 0.f, a2 = 0.f, a3 = 0.f;
    float b0 = 0.f, b1 = 0.f, b2 = 0.f, b3 = 0.f;
#pragma unroll
    for (int i = 0; i < 4; ++i) {
        v4f ra = *reinterpret_cast<v4f*>(&buf[i * 1024 + t * 4]);
        v4f rb = *reinterpret_cast<v4f*>(&buf[DIM + i * 1024 + t * 4]);
        a0 = fmaf(ra.x, xr[i].x, a0);
        a1 = fmaf(ra.y, xr[i].y, a1);
        a2 = fmaf(ra.z, xr[i].z, a2);
        a3 = fmaf(ra.w, xr[i].w, a3);
        b0 = fmaf(rb.x, xr[i].x, b0);
        b1 = fmaf(rb.y, xr[i].y, b1);
        b2 = fmaf(rb.z, xr[i].z, b2);
        b3 = fmaf(rb.w, xr[i].w, b3);
    }
    float da = wave_sum((a0 + a1) + (a2 + a3));
    float db = wave_sum((b0 + b1) + (b2 + b3));
    if (lane == 0) { red[0][w] = da; red[1][w] = db; }
    __syncthreads();
    if (t == 0) {
        float d0 = red[0][0] + red[0][1] + red[0][2] + red[0][3];
        float d1 = red[1][0] + red[1][1] + red[1][2] + red[1][3];
        int pos = *pos_p;
        int j = pr & 63;
        float theta = powf(10000.0f, -(float)(2 * j) / (float)D);
        float ang = (float)pos * theta;
        float s, c;
        sincosf(ang, &s, &c);
        float* o = isq ? xq : xk;
        o[2 * pr]     = d0 * c - d1 * s;
        o[2 * pr + 1] = d0 * s + d1 * c;
    }
}

__global__ void __launch_bounds__(256) v_mat(
        const float* __restrict__ wv, const float* __restrict__ x,
        float* __restrict__ xv) {
    __shared__ float red[4];
    int row = blockIdx.x;
    const float* w = wv + (size_t)row * DIM;
    int t = threadIdx.x;
    float acc = 0.f;
#pragma unroll
    for (int i = 0; i < 4; ++i) {
        int idx = (i * 256 + t) * 4;
        const float4 a = *reinterpret_cast<const float4*>(w + idx);
        const float4 b = *reinterpret_cast<const float4*>(x + idx);
        acc = fmaf(a.x, b.x, acc);
        acc = fmaf(a.y, b.y, acc);
        acc = fmaf(a.z, b.z, acc);
        acc = fmaf(a.w, b.w, acc);
    }
#pragma unroll
    for (int off = 32; off; off >>= 1) acc += __shfl_xor(acc, off);
    if ((t & 63) == 0) red[t >> 6] = acc;
    __syncthreads();
    if (t == 0) xv[row] = red[0] + red[1] + red[2] + red[3];
}

__device__ __forceinline__ void load_half(v4f (&buf)[8], const float* __restrict__ wp, int off) {
#pragma unroll
    for (int i = 0; i < 8; ++i)
        buf[i] = *reinterpret_cast<const v4f*>(wp + i * 256 + off);
}

template <int XO>
__device__ __forceinline__ float dot_half(const v4f (&buf)[8], const v4f (&xr)[16]) {
    float s0 = 0.f, s1 = 0.f, s2 = 0.f, s3 = 0.f;
#pragma unroll
    for (int i = 0; i < 8; ++i) {
        s0 = fmaf(buf[i].x, xr[XO + i].x, s0);
        s1 = fmaf(buf[i].y, xr[XO + i].y, s1);
        s2 = fmaf(buf[i].z, xr[XO + i].z, s2);
        s3 = fmaf(buf[i].w, xr[XO + i].w, s3);
    }
    return (s0 + s1) + (s2 + s3);
}

#define SB() __builtin_amdgcn_sched_barrier(0)

__global__ void __launch_bounds__(256) matvec_o(
        const float* __restrict__ w_, const float* __restrict__ vin,
        float* __restrict__ y) {
    int t = threadIdx.x, lane = t & 63;
    int W = blockIdx.x * 4 + (t >> 6);
    int r0 = W * 2;
    int off = lane * 4;

    v4f xr[16];
#pragma unroll
    for (int i = 0; i < 16; ++i)
        xr[i] = *reinterpret_cast<const v4f*>(vin + i * 256 + off);

    const float* w0 = w_ + (size_t)r0 * DIM;
    v4f A[8], B[8];
    float d0, d1;
    load_half(A, w0, off);
    load_half(B, w0 + 2048, off);            SB();
    d0  = dot_half<0>(A, xr);
    load_half(A, w0 + DIM, off);             SB();
    d0 += dot_half<8>(B, xr);
    load_half(B, w0 + DIM + 2048, off);      SB();
    d1  = dot_half<0>(A, xr);
    d1 += dot_half<8>(B, xr);

    d0 = wave_sum(d0); d1 = wave_sum(d1);
    if (lane == 0) { y[r0] = d0; y[r0 + 1] = d1; }
}

__global__ void attn_partial(const float* __restrict__ cache_k, const float* __restrict__ cache_v,
                             const float* __restrict__ xq, const float* __restrict__ xk,
                             const float* __restrict__ xv, const int* __restrict__ pos_p,
                             float* __restrict__ partials) {
    __shared__ float lds_m[4], lds_l[4];
    __shared__ float lds_acc[4][128];
    int h = blockIdx.x;
    int c = blockIdx.y;
    int lane = threadIdx.x;
    int g  = lane >> 4;
    int gl = lane & 15;
    int pos = *pos_p;
    int base = c * CHUNK;
    int p1 = min(base + CHUNK, pos + 1);
    float* pp = partials + (size_t)(h * NCHUNK + c) * PART_STRIDE;

    if (base > pos) {
        if (lane == 0) { pp[128] = -INFINITY; pp[129] = 0.f; }
        reinterpret_cast<float2*>(pp)[lane] = make_float2(0.f, 0.f);
        return;
    }

    const float4* qv = reinterpret_cast<const float4*>(xq + h * D + gl * 8);
    const float4 q0 = qv[0], q1 = qv[1];

    float m = -INFINITY, l = 0.f;
    float4 acc0 = make_float4(0.f, 0.f, 0.f, 0.f);
    float4 acc1 = make_float4(0.f, 0.f, 0.f, 0.f);

    for (int p = base + g; p < p1; p += 4) {
        const float* kp = (p == pos) ? (xk + h * D)
                                     : (cache_k + ((size_t)p * H + h) * D);
        const float4* kv4 = reinterpret_cast<const float4*>(kp + gl * 8);
        float4 k0 = kv4[0], k1 = kv4[1];
        float d = q0.x * k0.x + q0.y * k0.y + q0.z * k0.z + q0.w * k0.w
                + q1.x * k1.x + q1.y * k1.y + q1.z * k1.z + q1.w * k1.w;
        d += __shfl_xor(d, 1);
        d += __shfl_xor(d, 2);
        d += __shfl_xor(d, 4);
        d += __shfl_xor(d, 8);
        float s = d * 0.08838834764831845f;
        float mn = fmaxf(m, s);
        float corr = __expf(m - mn);
        float wgt  = __expf(s - mn);
        const float* vp = (p == pos) ? (xv + h * D)
                                     : (cache_v + ((size_t)p * H + h) * D);
        const float4* vv4 = reinterpret_cast<const float4*>(vp + gl * 8);
        float4 v0 = vv4[0], v1 = vv4[1];
        l = l * corr + wgt;
        acc0.x = fmaf(wgt, v0.x, acc0.x * corr);
        acc0.y = fmaf(wgt, v0.y, acc0.y * corr);
        acc0.z = fmaf(wgt, v0.z, acc0.z * corr);
        acc0.w = fmaf(wgt, v0.w, acc0.w * corr);
        acc1.x = fmaf(wgt, v1.x, acc1.x * corr);
        acc1.y = fmaf(wgt, v1.y, acc1.y * corr);
        acc1.z = fmaf(wgt, v1.z, acc1.z * corr);
        acc1.w = fmaf(wgt, v1.w, acc1.w * corr);
        m = mn;
    }

    if (gl == 0) { lds_m[g] = m; lds_l[g] = l; }
    *reinterpret_cast<float4*>(&lds_acc[g][gl * 8])     = acc0;
    *reinterpret_cast<float4*>(&lds_acc[g][gl * 8 + 4]) = acc1;
    __syncthreads();
    float M = fmaxf(fmaxf(lds_m[0], lds_m[1]), fmaxf(lds_m[2], lds_m[3]));
    float w0 = __expf(lds_m[0] - M);
    float w1 = __expf(lds_m[1] - M);
    float w2 = __expf(lds_m[2] - M);
    float w3 = __expf(lds_m[3] - M);
    float L  = w0 * lds_l[0] + w1 * lds_l[1] + w2 * lds_l[2] + w3 * lds_l[3];
    int d0 = 2 * lane;
    float s0 = w0 * lds_acc[0][d0]     + w1 * lds_acc[1][d0]
             + w2 * lds_acc[2][d0]     + w3 * lds_acc[3][d0];
    float s1 = w0 * lds_acc[0][d0 + 1] + w1 * lds_acc[1][d0 + 1]
             + w2 * lds_acc[2][d0 + 1] + w3 * lds_acc[3][d0 + 1];
    if (lane == 0) { pp[128] = M; pp[129] = L; }
    reinterpret_cast<float2*>(pp)[lane] = make_float2(s0, s1);
}

__global__ void attn_combine(const float* __restrict__ partials, float* __restrict__ out_attn) {
    int h = blockIdx.x;
    int lane = threadIdx.x;
    float m = -INFINITY;
    for (int c = 0; c < NCHUNK; ++c)
        m = fmaxf(m, partials[(size_t)(h * NCHUNK + c) * PART_STRIDE + 128]);
    float L = 0.f, a0 = 0.f, a1 = 0.f;
    for (int c = 0; c < NCHUNK; ++c) {
        const float* pp = partials + (size_t)(h * NCHUNK + c) * PART_STRIDE;
        float mw = pp[128];
        float w = (mw == -INFINITY) ? 0.f : __expf(mw - m);
        L += pp[129] * w;
        float2 a = *reinterpret_cast<const float2*>(pp + 2 * lane);
        a0 += w * a.x;
        a1 += w * a.y;
    }
    float inv = 1.f / L;
    out_attn[h * D + 2 * lane]     = a0 * inv;
    out_attn[h * D + 2 * lane + 1] = a1 * inv;
}

extern "C" void kernel_launch(void* const* d_in, const int* in_sizes, int n_in,
                              void* d_out, int out_size, void* d_ws, size_t ws_size,
                              hipStream_t stream) {
    const float* x       = (const float*)d_in[0];
    const float* wq      = (const float*)d_in[1];
    const float* wk      = (const float*)d_in[2];
    const float* wv      = (const float*)d_in[3];
    const float* wo      = (const float*)d_in[4];
    const float* cache_k = (const float*)d_in[5];
    const float* cache_v = (const float*)d_in[6];
    const int*   pos     = (const int*)d_in[7];

    float* wsf      = (float*)d_ws;
    float* xq       = wsf;
    float* xk       = wsf + DIM;
    float* xv       = wsf + 2 * DIM;
    float* partials = wsf + 3 * DIM;
    float* out_attn = partials + H * NCHUNK * PART_STRIDE;
    float* y        = (float*)d_out;

    // host-side gating (deterministic, capture-safe)
    int dev = 0;
    hipGetDevice(&dev);
    int coop_ok = 0, n_cu = 0, occ = 0;
    hipDeviceGetAttribute(&coop_ok, hipDeviceAttributeCooperativeLaunch, dev);
    hipDeviceGetAttribute(&n_cu, hipDeviceAttributeMultiprocessorCount, dev);
    hipOccupancyMaxActiveBlocksPerMultiprocessor(&occ, fused_decode, NTHR, 0);

    if (coop_ok && occ > 0 && (long)occ * n_cu >= NBLK) {
        void* args[] = {
            (void*)&wq, (void*)&wk, (void*)&wv, (void*)&wo, (void*)&x,
            (void*)&cache_k, (void*)&cache_v, (void*)&pos,
            (void*)&xq, (void*)&xk, (void*)&xv,
            (void*)&partials, (void*)&out_attn, (void*)&y
        };
        hipError_t e = hipLaunchCooperativeKernel((const void*)fused_decode,
                                                  dim3(NBLK), dim3(NTHR), args, 0, stream);
        if (e == hipSuccess) return;
    }

    // fallback: proven 5-kernel pipeline
    qk_rope<<<4096, 256, 0, stream>>>(wq, wk, x, pos, xq, xk);
    v_mat<<<DIM, 256, 0, stream>>>(wv, x, xv);
    attn_partial<<<dim3(H, NCHUNK), 64, 0, stream>>>(cache_k, cache_v, xq, xk, xv, pos, partials);
    attn_combine<<<H, 64, 0, stream>>>(partials, out_attn);
    matvec_o<<<512, 256, 0, stream>>>(wo, out_attn, y);
}